// Round 6
// baseline (10214.088 us; speedup 1.0000x reference)
//
#include <hip/hip_runtime.h>

// Pendulum 3-layer LSTM (H=128), B=256 rows, 1024 sequential steps.
// Head collapsed to y = weff.h3 + beff (exact fp32 precompute).
// 128 blocks x 512 threads, 2 rows/block. Thread = (idx in 128, kq in 4).
//   L1 weights (128KB): LDS-resident, bank-swizzled, loaded once.
//   L2 weights (256KB): register-resident (32 uint4 = 128 VGPRs).
//   L3 weights (256KB): streamed global->VGPR via persistent 8-slot ring;
//     Whh3*h3_old half interleaved with L2 dots, Wih3*h2_new half interleaved
//     with the NEXT step's L1 dots (cross-step software pipeline).
// 3 barriers/step, raw s_barrier + lgkmcnt(0) only (ring survives barriers).
//
// ROUND 6 CHANGE (one lever, isolates the spill theory):
//   __launch_bounds__(512, 2) -> (512, 1).
//   Rounds 3/4/5 all pinned VGPR_Count=128 with WRITE_SIZE ~1.6GB of scratch
//   spills: hipcc treats the 2nd arg as 2 blocks/CU -> 4 waves/SIMD -> 128-reg
//   cap. LDS (139.5KB) limits to 1 block/CU anyway, so the cap bought nothing.
//   (512,1) -> 2 waves/SIMD -> 256-reg cap >= ~230-reg demand -> no spill.

typedef _Float16 f16;
typedef _Float16 f16x2 __attribute__((ext_vector_type(2)));
typedef unsigned int u32;

#define T_IN 512
#define T_TOT 1024
#define NBLK 128

__device__ __forceinline__ f16x2 u2h(u32 u) { return __builtin_bit_cast(f16x2, u); }

__device__ __forceinline__ float fdot2f(f16x2 a, f16x2 b, float c) {
#if __has_builtin(__builtin_amdgcn_fdot2)
  return __builtin_amdgcn_fdot2(a, b, c, false);
#else
  return c + (float)a[0] * (float)b[0] + (float)a[1] * (float)b[1];
#endif
}

__device__ __forceinline__ float frcp(float x) {
#if __has_builtin(__builtin_amdgcn_rcpf)
  return __builtin_amdgcn_rcpf(x);
#else
  return 1.f / x;
#endif
}
__device__ __forceinline__ float fsigm(float x) { return frcp(1.f + __expf(-x)); }
__device__ __forceinline__ float ftanh(float x) { return 1.f - 2.f * frcp(1.f + __expf(2.f * x)); }

#define DOT4(acc, w, hv)                     \
  do {                                       \
    f16x2 _h = u2h(hv);                      \
    acc[0] = fdot2f(u2h((w).x), _h, acc[0]); \
    acc[1] = fdot2f(u2h((w).y), _h, acc[1]); \
    acc[2] = fdot2f(u2h((w).z), _h, acc[2]); \
    acc[3] = fdot2f(u2h((w).w), _h, acc[3]); \
  } while (0)

// ---- weight packing -------------------------------------------------------
// Std layout: uint4 at [pair p][idx], u32 slot g: half2{W[g*128+idx][2p],[2p+1]}
__global__ void pack_cat(u32* dst, const float* A, const float* Bm, int Pa, int P) {
  int tid = blockIdx.x * 256 + threadIdx.x;
  if (tid >= P * 512) return;
  int g = tid & 3;
  int idx = (tid >> 2) & 127;
  int p = tid >> 9;
  int j = g * 128 + idx;
  const float* src;
  int k;
  if (p < Pa) { src = A; k = 2 * p; } else { src = Bm; k = 2 * (p - Pa); }
  union { f16 h[2]; u32 u; } cv;
  cv.h[0] = (f16)src[j * 128 + k];
  cv.h[1] = (f16)src[j * 128 + k + 1];
  dst[tid] = cv.u;
}

// L1 (Whh1 only, 64 pairs), bank-swizzled: slot = p*128 + (idx ^ (2*(p>>4)))
__global__ void pack1(u32* dst, const float* Whh1) {
  int tid = blockIdx.x * 256 + threadIdx.x;
  if (tid >= 64 * 512) return;
  int g = tid & 3;
  int idx = (tid >> 2) & 127;
  int p = tid >> 9;
  int j = g * 128 + idx;
  union { f16 h[2]; u32 u; } cv;
  cv.h[0] = (f16)Whh1[j * 128 + 2 * p];
  cv.h[1] = (f16)Whh1[j * 128 + 2 * p + 1];
  dst[(p * 128 + (idx ^ (2 * (p >> 4)))) * 4 + g] = cv.u;
}

// L3 stream order: uint4 index = i*512 + idx*4 + kq, i = consumption order.
// i<16 (early): p = 64 + kq*16 + i  (Whh3, vs h3_old pair kq*16+i)
// i>=16 (late): p = kq*16 + (i-16)  (Wih3, vs h2_new pair kq*16+(i-16))
__global__ void pack3(u32* dst, const float* Wih3, const float* Whh3) {
  int tid = blockIdx.x * 256 + threadIdx.x;
  if (tid >= 128 * 512) return;
  int g = tid & 3;
  int u4i = tid >> 2;
  int kq = u4i & 3;
  int idx = (u4i >> 2) & 127;
  int i = u4i >> 9;
  int p = (i < 16) ? (64 + kq * 16 + i) : (kq * 16 + (i - 16));
  int j = g * 128 + idx;
  const float* src = (p < 64) ? Wih3 : Whh3;
  int k = (p < 64) ? 2 * p : 2 * (p - 64);
  union { f16 h[2]; u32 u; } cv;
  cv.h[0] = (f16)src[j * 128 + k];
  cv.h[1] = (f16)src[j * 128 + k + 1];
  dst[tid] = cv.u;
}

// consT[gg*512 + g*128 + idx]: gg 0=b1,1=b2,2=b3,3=wih1. [2048+idx]=weff, [2176]=beff.
__global__ void prep_cons(float* cons, const float* a1, const float* b1,
                          const float* a2, const float* b2,
                          const float* a3, const float* b3, const float* wih1) {
  int tid = blockIdx.x * 256 + threadIdx.x;
  if (tid >= 2048) return;
  int gg = tid >> 9, g = (tid >> 7) & 3, idx = tid & 127;
  int j = g * 128 + idx;
  float v;
  if (gg == 0) v = a1[j] + b1[j];
  else if (gg == 1) v = a2[j] + b2[j];
  else if (gg == 2) v = a3[j] + b3[j];
  else v = wih1[j];
  cons[tid] = v;
}

__global__ void head_fold(float* cons, const float* lin_w, const float* out_w,
                          const float* Wv, const float* bv,
                          const float* out_b, const float* lin_b) {
  __shared__ float wlo[128];
  __shared__ float pr[128];
  int j = threadIdx.x;
  float s = 0.f;
  for (int k = 0; k < 128; ++k) s += lin_w[k] * out_w[k * 128 + j];
  wlo[j] = s;
  __syncthreads();
  float t = 0.f;
  for (int k = 0; k < 128; ++k) t += wlo[k] * Wv[k * 128 + j];
  cons[2048 + j] = t;
  pr[j] = s * bv[j] + lin_w[j] * out_b[j];
  __syncthreads();
  if (j == 0) {
    float b = lin_b[0];
    for (int k = 0; k < 128; ++k) b += pr[k];
    cons[2176] = b;
  }
}

// ---- main persistent kernel ----------------------------------------------
__global__ __launch_bounds__(512, 1) void pendulum_persist(
    const float* __restrict__ input, const uint4* __restrict__ WT1g,
    const uint4* __restrict__ WT2, const uint4* __restrict__ WT3r,
    const float* __restrict__ consG, float* __restrict__ out) {
  __shared__ __align__(16) uint4 w1lds[8192];   // 128 KB, swizzled L1
  __shared__ __align__(16) f16 h1b[2][2][128];  // [parity][row][idx]
  __shared__ __align__(16) f16 h2b[2][2][128];
  __shared__ __align__(16) f16 h3b[2][128];     // [row][idx], single buffer
  __shared__ float consL[2180];
  __shared__ float redp[2][8];

  const int t = threadIdx.x;
  const int idx = t >> 2;
  const int kq = t & 3;
  const int row0 = blockIdx.x * 2, row1 = row0 + 1;

  for (int e = t; e < 8192; e += 512) w1lds[e] = WT1g[e];
  for (int e = t; e < 2177; e += 512) consL[e] = consG[e];
  if (t < 128) {
    h1b[0][0][t] = (f16)0.f; h1b[0][1][t] = (f16)0.f;
    h1b[1][0][t] = (f16)0.f; h1b[1][1][t] = (f16)0.f;
    h2b[0][0][t] = (f16)0.f; h2b[0][1][t] = (f16)0.f;
    h2b[1][0][t] = (f16)0.f; h2b[1][1][t] = (f16)0.f;
    h3b[0][t] = (f16)0.f;    h3b[1][t] = (f16)0.f;
  }

  uint4 w2r[32];
#pragma unroll
  for (int j = 0; j < 32; ++j) w2r[j] = WT2[(kq * 32 + j) * 128 + idx];

  const uint4* W3p = WT3r + t;
  const uint4* w1p = w1lds + kq * 2048 + (idx ^ (2 * kq));

  float c1a = 0.f, c1b = 0.f, c2a = 0.f, c2b = 0.f, c3a = 0.f, c3b = 0.f;
  float y0 = 0.f, y1 = 0.f;
  __syncthreads();
  const float beffv = consL[2176];

  // prologue: step-0 layer1 (h1_old = 0 -> no dots)
  {
    float x0 = input[row0 * T_IN], x1 = input[row1 * T_IN];
    if (kq == 0) {
      float b0 = consL[idx], b1v = consL[128 + idx], b2v = consL[256 + idx],
            b3v = consL[384 + idx];
      float w0 = consL[1536 + idx], w1w = consL[1664 + idx],
            w2w = consL[1792 + idx], w3w = consL[1920 + idx];
      {
        float ig = fsigm(b0 + x0 * w0), fg = fsigm(b1v + x0 * w1w);
        float gg = ftanh(b2v + x0 * w2w), og = fsigm(b3v + x0 * w3w);
        (void)fg; c1a = ig * gg; h1b[0][0][idx] = (f16)(og * ftanh(c1a));
      }
      {
        float ig = fsigm(b0 + x1 * w0), fg = fsigm(b1v + x1 * w1w);
        float gg = ftanh(b2v + x1 * w2w), og = fsigm(b3v + x1 * w3w);
        (void)fg; c1b = ig * gg; h1b[0][1][idx] = (f16)(og * ftanh(c1b));
      }
    }
    __syncthreads();
  }

  // ring prologue: loads c=0..7 (early chunk of step 0)
  uint4 ring[8];
#pragma unroll
  for (int c = 0; c < 8; ++c) ring[c] = W3p[c * 512];

  for (int s = 0; s < T_TOT; ++s) {
    const int par = s & 1;
    const int xi = (s + 1 < T_IN) ? (s + 1) : 0;
    float xl0 = input[row0 * T_IN + xi];
    float xl1 = input[row1 * T_IN + xi];

    const uint4* hL2r0 = (kq < 2)
        ? (const uint4*)&h1b[par][0][0] + kq * 8
        : (const uint4*)&h2b[par ^ 1][0][0] + (kq - 2) * 8;
    const uint4* hL2r1 = (kq < 2)
        ? (const uint4*)&h1b[par][1][0] + kq * 8
        : (const uint4*)&h2b[par ^ 1][1][0] + (kq - 2) * 8;
    const uint4* h3r0 = (const uint4*)&h3b[0][0] + kq * 4;
    const uint4* h3r1 = (const uint4*)&h3b[1][0] + kq * 4;

    float a2r0[4] = {0, 0, 0, 0}, a2r1[4] = {0, 0, 0, 0};
    float a3r0[4] = {0, 0, 0, 0}, a3r1[4] = {0, 0, 0, 0};

    // ---- P_A: L2 dots (32 u4) + L3-early dots (16 u4, ring) ----
    uint4 E0, E1;
#pragma unroll
    for (int q = 0; q < 8; ++q) {
      uint4 H0 = hL2r0[q], H1 = hL2r1[q];
      u32 e0[4] = {H0.x, H0.y, H0.z, H0.w};
      u32 e1[4] = {H1.x, H1.y, H1.z, H1.w};
#pragma unroll
      for (int e = 0; e < 4; ++e) {
        uint4 w = w2r[q * 4 + e];
        DOT4(a2r0, w, e0[e]);
        DOT4(a2r1, w, e1[e]);
      }
      if ((q & 1) == 0) { E0 = h3r0[q >> 1]; E1 = h3r1[q >> 1]; }
      {
        uint4 w = ring[(2 * q) & 7];
        ring[(2 * q) & 7] = W3p[(2 * q + 8) * 512];
        u32 h0 = (q & 1) ? E0.z : E0.x, h1v = (q & 1) ? E1.z : E1.x;
        DOT4(a3r0, w, h0);
        DOT4(a3r1, w, h1v);
      }
      {
        uint4 w = ring[(2 * q + 1) & 7];
        ring[(2 * q + 1) & 7] = W3p[(2 * q + 9) * 512];
        u32 h0 = (q & 1) ? E0.w : E0.y, h1v = (q & 1) ? E1.w : E1.y;
        DOT4(a3r0, w, h0);
        DOT4(a3r1, w, h1v);
      }
    }

    // L2 finish
#pragma unroll
    for (int g = 0; g < 4; ++g) {
      a2r0[g] += __shfl_xor(a2r0[g], 1, 64); a2r0[g] += __shfl_xor(a2r0[g], 2, 64);
      a2r1[g] += __shfl_xor(a2r1[g], 1, 64); a2r1[g] += __shfl_xor(a2r1[g], 2, 64);
    }
    if (kq == 0) {
      float b0 = consL[512 + idx], b1v = consL[640 + idx],
            b2v = consL[768 + idx], b3v = consL[896 + idx];
      {
        float ig = fsigm(a2r0[0] + b0), fg = fsigm(a2r0[1] + b1v);
        float gg = ftanh(a2r0[2] + b2v), og = fsigm(a2r0[3] + b3v);
        c2a = fg * c2a + ig * gg;
        h2b[par][0][idx] = (f16)(og * ftanh(c2a));
      }
      {
        float ig = fsigm(a2r1[0] + b0), fg = fsigm(a2r1[1] + b1v);
        float gg = ftanh(a2r1[2] + b2v), og = fsigm(a2r1[3] + b3v);
        c2b = fg * c2b + ig * gg;
        h2b[par][1][idx] = (f16)(og * ftanh(c2b));
      }
    }
    asm volatile("s_waitcnt lgkmcnt(0)\n\ts_barrier" ::: "memory");  // barrier1

    // ---- P_B: L3-late dots (16 u4, ring) + L1 dots for step s+1 (16 u4) ----
    const uint4* hLTr0 = (const uint4*)&h2b[par][0][0] + kq * 4;
    const uint4* hLTr1 = (const uint4*)&h2b[par][1][0] + kq * 4;
    const uint4* h1r0 = (const uint4*)&h1b[par][0][0] + kq * 4;
    const uint4* h1r1 = (const uint4*)&h1b[par][1][0] + kq * 4;

    float a1r0[4] = {0, 0, 0, 0}, a1r1[4] = {0, 0, 0, 0};
    uint4 L0, L1v, F0, F1;
#pragma unroll
    for (int q = 0; q < 8; ++q) {
      if ((q & 1) == 0) {
        L0 = hLTr0[q >> 1]; L1v = hLTr1[q >> 1];
        F0 = h1r0[q >> 1];  F1 = h1r1[q >> 1];
      }
      {
        uint4 w = ring[(2 * q) & 7];
        ring[(2 * q) & 7] = W3p[(((16 + 2 * q) + 8) & 31) * 512];
        u32 h0 = (q & 1) ? L0.z : L0.x, h1x = (q & 1) ? L1v.z : L1v.x;
        DOT4(a3r0, w, h0);
        DOT4(a3r1, w, h1x);
      }
      {
        uint4 w = ring[(2 * q + 1) & 7];
        ring[(2 * q + 1) & 7] = W3p[(((17 + 2 * q) + 8) & 31) * 512];
        u32 h0 = (q & 1) ? L0.w : L0.y, h1x = (q & 1) ? L1v.w : L1v.y;
        DOT4(a3r0, w, h0);
        DOT4(a3r1, w, h1x);
      }
      {
        uint4 w = w1p[(2 * q) * 128];
        u32 h0 = (q & 1) ? F0.z : F0.x, h1x = (q & 1) ? F1.z : F1.x;
        DOT4(a1r0, w, h0);
        DOT4(a1r1, w, h1x);
      }
      {
        uint4 w = w1p[(2 * q + 1) * 128];
        u32 h0 = (q & 1) ? F0.w : F0.y, h1x = (q & 1) ? F1.w : F1.y;
        DOT4(a1r0, w, h0);
        DOT4(a1r1, w, h1x);
      }
    }

#pragma unroll
    for (int g = 0; g < 4; ++g) {
      a3r0[g] += __shfl_xor(a3r0[g], 1, 64); a3r0[g] += __shfl_xor(a3r0[g], 2, 64);
      a3r1[g] += __shfl_xor(a3r1[g], 1, 64); a3r1[g] += __shfl_xor(a3r1[g], 2, 64);
      a1r0[g] += __shfl_xor(a1r0[g], 1, 64); a1r0[g] += __shfl_xor(a1r0[g], 2, 64);
      a1r1[g] += __shfl_xor(a1r1[g], 1, 64); a1r1[g] += __shfl_xor(a1r1[g], 2, 64);
    }

    // L3 finish + head partial
    float p0 = 0.f, p1 = 0.f;
    if (kq == 0) {
      float b0 = consL[1024 + idx], b1v = consL[1152 + idx],
            b2v = consL[1280 + idx], b3v = consL[1408 + idx];
      float weffr = consL[2048 + idx];
      {
        float ig = fsigm(a3r0[0] + b0), fg = fsigm(a3r0[1] + b1v);
        float gg = ftanh(a3r0[2] + b2v), og = fsigm(a3r0[3] + b3v);
        c3a = fg * c3a + ig * gg;
        float h3 = og * ftanh(c3a);
        h3b[0][idx] = (f16)h3;
        p0 = weffr * h3;
      }
      {
        float ig = fsigm(a3r1[0] + b0), fg = fsigm(a3r1[1] + b1v);
        float gg = ftanh(a3r1[2] + b2v), og = fsigm(a3r1[3] + b3v);
        c3b = fg * c3b + ig * gg;
        float h3 = og * ftanh(c3b);
        h3b[1][idx] = (f16)h3;
        p1 = weffr * h3;
      }
    }
#pragma unroll
    for (int k = 1; k < 64; k <<= 1) {
      p0 += __shfl_xor(p0, k, 64);
      p1 += __shfl_xor(p1, k, 64);
    }
    if ((t & 63) == 0) { redp[0][t >> 6] = p0; redp[1][t >> 6] = p1; }
    asm volatile("s_waitcnt lgkmcnt(0)\n\ts_barrier" ::: "memory");  // barrier2

    y0 = beffv; y1 = beffv;
#pragma unroll
    for (int w8 = 0; w8 < 8; ++w8) { y0 += redp[0][w8]; y1 += redp[1][w8]; }
    if (t == 0) out[row0 * T_TOT + s] = y0;
    else if (t == 1) out[row1 * T_TOT + s] = y1;

    // L1 finish for step s+1
    float xv0 = (s + 1 < T_IN) ? xl0 : y0;
    float xv1 = (s + 1 < T_IN) ? xl1 : y1;
    if (kq == 0) {
      float b0 = consL[idx], b1v = consL[128 + idx], b2v = consL[256 + idx],
            b3v = consL[384 + idx];
      float w0 = consL[1536 + idx], w1w = consL[1664 + idx],
            w2w = consL[1792 + idx], w3w = consL[1920 + idx];
      {
        float ig = fsigm(a1r0[0] + b0 + xv0 * w0), fg = fsigm(a1r0[1] + b1v + xv0 * w1w);
        float gg = ftanh(a1r0[2] + b2v + xv0 * w2w), og = fsigm(a1r0[3] + b3v + xv0 * w3w);
        c1a = fg * c1a + ig * gg;
        h1b[par ^ 1][0][idx] = (f16)(og * ftanh(c1a));
      }
      {
        float ig = fsigm(a1r1[0] + b0 + xv1 * w0), fg = fsigm(a1r1[1] + b1v + xv1 * w1w);
        float gg = ftanh(a1r1[2] + b2v + xv1 * w2w), og = fsigm(a1r1[3] + b3v + xv1 * w3w);
        c1b = fg * c1b + ig * gg;
        h1b[par ^ 1][1][idx] = (f16)(og * ftanh(c1b));
      }
    }
    asm volatile("s_waitcnt lgkmcnt(0)\n\ts_barrier" ::: "memory");  // barrier3
  }
}

// ---- launch ---------------------------------------------------------------
extern "C" void kernel_launch(void* const* d_in, const int* in_sizes, int n_in,
                              void* d_out, int out_size, void* d_ws, size_t ws_size,
                              hipStream_t stream) {
  const float* input = (const float*)d_in[0];
  const float* Wih1 = (const float*)d_in[2];
  const float* Whh1 = (const float*)d_in[3];
  const float* bih1 = (const float*)d_in[4];
  const float* bhh1 = (const float*)d_in[5];
  const float* Wih2 = (const float*)d_in[6];
  const float* Whh2 = (const float*)d_in[7];
  const float* bih2 = (const float*)d_in[8];
  const float* bhh2 = (const float*)d_in[9];
  const float* Wih3 = (const float*)d_in[10];
  const float* Whh3 = (const float*)d_in[11];
  const float* bih3 = (const float*)d_in[12];
  const float* bhh3 = (const float*)d_in[13];
  const float* in_proj_w = (const float*)d_in[14];
  const float* in_proj_b = (const float*)d_in[15];
  const float* out_w = (const float*)d_in[16];
  const float* out_b = (const float*)d_in[17];
  const float* lin_w = (const float*)d_in[18];
  const float* lin_b = (const float*)d_in[19];

  char* ws = (char*)d_ws;
  u32* WT1 = (u32*)(ws + (0 << 10));    // 128 KB swizzled L1
  u32* WT2 = (u32*)(ws + (128 << 10));  // 256 KB std L2
  u32* WT3r = (u32*)(ws + (384 << 10)); // 256 KB stream-ordered L3
  float* consG = (float*)(ws + (640 << 10)); // ~8.7 KB

  pack1<<<128, 256, 0, stream>>>(WT1, Whh1);
  pack_cat<<<256, 256, 0, stream>>>(WT2, Wih2, Whh2, 64, 128);
  pack3<<<256, 256, 0, stream>>>(WT3r, Wih3, Whh3);
  prep_cons<<<8, 256, 0, stream>>>(consG, bih1, bhh1, bih2, bhh2, bih3, bhh3, Wih1);
  head_fold<<<1, 128, 0, stream>>>(consG, lin_w, out_w,
                                   in_proj_w + 2 * 128 * 128, in_proj_b + 256,
                                   out_b, lin_b);

  pendulum_persist<<<NBLK, 512, 0, stream>>>(
      input, (const uint4*)WT1, (const uint4*)WT2, (const uint4*)WT3r,
      consG, (float*)d_out);
}